// Round 4
// baseline (272.438 us; speedup 1.0000x reference)
//
#include <hip/hip_runtime.h>
#include <stdint.h>

// Problem constants
#define B_SZ   8192
#define IN_DIM 320      // S + A
#define H_DIM  1024
#define E_NUM  8
#define OUT_DIM 257     // S + 1
#define TM     64
#define MAXT   (B_SZ / TM + E_NUM)   // 136 — worst-case M-tile count
#define W3ROWS 320                   // layer-3 N padded to 5 x 64
#define NG12   (MAXT * 16)           // 2176 gemm blocks, layers 1/2
#define NG3    (MAXT * 5)            // 680 gemm blocks, layer 3
#define NAUX   2568                  // 2048 W2T + 512 W3T + 8 rcol

typedef __bf16 bf16x8 __attribute__((ext_vector_type(8)));
typedef float  f32x4  __attribute__((ext_vector_type(4)));

typedef unsigned int __attribute__((address_space(1))) as1_uint;
typedef unsigned int __attribute__((address_space(3))) as3_uint;

__device__ __forceinline__ void gload_lds16(const void* g, void* l) {
    __builtin_amdgcn_global_load_lds((const as1_uint*)g, (as3_uint*)l, 16, 0, 0);
}

__device__ __forceinline__ unsigned short f2bf(float f) {
    unsigned int u = __float_as_uint(f);
    return (unsigned short)((u + 0x7fffu + ((u >> 16) & 1u)) >> 16);  // RNE
}

// ---------------------------------------------------------------------------
// 64x64 transpose-convert: src (e, Ks, Ns) f32 tile (k0,n0) -> dst (e, dR, Ks)
// bf16 rows n0..n0+63. Works for any thread count that's a multiple of 64.
// sh: 64*66 ushorts. Phase-2: ushort4 (8 B) stores, 4 n-rows x 128 B per instr.
__device__ __forceinline__ void trans64(const float* __restrict__ src,
                                        unsigned short* __restrict__ dst,
                                        int Ks, int Ns, int dR, int e, int kt,
                                        int nt, unsigned short* sh,
                                        int tid, int nthr) {
    int k0 = kt * 64, n0 = nt * 64;
    const float* s = src + (size_t)e * Ks * Ns + (size_t)k0 * Ns + n0;
    unsigned short* d = dst + ((size_t)e * dR + n0) * Ks + k0;
    int tx = tid & 63, wv = tid >> 6, nw = nthr >> 6;
    for (int rr = wv; rr < 64; rr += nw)
        sh[rr * 66 + tx] = f2bf(s[(size_t)rr * Ns + tx]);
    __syncthreads();
    int kq = tid & 15, nr = (tid >> 4) & 3;
    for (int p = 0; p < 16 / nw; p++) {
        int n = (wv + p * nw) * 4 + nr;
        ushort4 o;
        o.x = sh[(kq * 4 + 0) * 66 + n];
        o.y = sh[(kq * 4 + 1) * 66 + n];
        o.z = sh[(kq * 4 + 2) * 66 + n];
        o.w = sh[(kq * 4 + 3) * 66 + n];
        *(ushort4*)&d[(size_t)n * Ks + kq * 4] = o;
    }
}

// ---------------------------------------------------------------------------
// prep0: bucket + x-convert + W1 transpose.  256 threads.
// grid: 1 (bucket) + 320 (xconv) + 640 (W1T) = 961
__global__ __launch_bounds__(256)
void k_prep0(const float* __restrict__ state, const float* __restrict__ action,
             const int* __restrict__ idx, const float* __restrict__ W1,
             unsigned short* __restrict__ xb, unsigned short* __restrict__ w1t,
             int* __restrict__ order, int* __restrict__ te,
             int* __restrict__ tp0, int* __restrict__ tcnt) {
    __shared__ unsigned short sh[64 * 66];
    __shared__ int scnt[16][E_NUM];
    int bid = blockIdx.x, tid = threadIdx.x;

    if (bid == 0) {
        int shard = tid & 15;
        if (tid < 128) ((int*)scnt)[tid] = 0;
        __syncthreads();
        for (int b = tid; b < B_SZ; b += 256) atomicAdd(&scnt[shard][idx[b]], 1);
        __syncthreads();
        if (tid == 0) {
            int pos = 0, tt = 0;
            for (int e = 0; e < E_NUM; e++) {
                int start = pos;
                for (int s = 0; s < 16; s++) { int c = scnt[s][e]; scnt[s][e] = pos; pos += c; }
                int tot = pos - start;
                for (int st = 0; st < tot; st += TM) {
                    te[tt] = e; tp0[tt] = start + st; tcnt[tt] = min(TM, tot - st); tt++;
                }
            }
            for (; tt < MAXT; tt++) { te[tt] = 0; tp0[tt] = 0; tcnt[tt] = 0; }
        }
        __syncthreads();
        for (int b = tid; b < B_SZ; b += 256) {
            int e = idx[b];
            int p = atomicAdd(&scnt[shard][e], 1);
            order[p] = b;
        }
        return;
    }

    if (bid <= 320) {
        // x = concat(state, action) -> bf16; 2048 quads per block (exact: 320*2048)
        int a = bid - 1;
        const float4* sf = (const float4*)state;
        const float4* af = (const float4*)action;
#pragma unroll
        for (int p = 0; p < 8; p++) {
            int q = a * 2048 + p * 256 + tid;     // quad id: b*80 + j
            int b = q / 80, j = q % 80;
            float4 v = (j < 64) ? sf[b * 64 + j] : af[b * 16 + (j - 64)];
            ushort4 o;
            o.x = f2bf(v.x); o.y = f2bf(v.y); o.z = f2bf(v.z); o.w = f2bf(v.w);
            ((ushort4*)xb)[q] = o;
        }
        return;
    }

    // W1 transpose: (8,320,1024) -> (8,1024,320); 80 tiles/e
    int c = bid - 321;
    int e = c / 80, m = c % 80, kt = m / 16, nt = m % 16;
    trans64(W1, w1t, IN_DIM, H_DIM, H_DIM, e, kt, nt, sh, tid, 256);
}

// ---------------------------------------------------------------------------
// Grouped GEMM: single-wave blocks (64 thr), 64x64 tile, BK=32, 2-stage LDS
// double buffer, XOR-swizzled (slot (row,c) holds global chunk c^((row>>1)&3)).
// Wt: (E, wtRows, K) bf16 N-major. 16 KB LDS -> 10 blocks/CU resident.
// MODE 0: Hout[(p0+m)*1024 + n] = bf16(relu(acc + bias))
// MODE 1: n<256 -> Out[row*256+n] = state+acc+b; n==256 -> reward; else drop.
// AUX: blocks [ng, ng+2568) do W2/W3 transpose + W3 reward column instead.
template <int K, bool GATHER, int MODE, bool AUX>
__global__ __launch_bounds__(64, 2)
void k_gemm(const unsigned short* __restrict__ Abase,
            const unsigned short* __restrict__ Wt, int wtRows,
            const float* __restrict__ bias, int bstride,
            unsigned short* __restrict__ Hout,
            float* __restrict__ Out, const float* __restrict__ state,
            const int* __restrict__ order,
            const int* __restrict__ te, const int* __restrict__ tp0,
            const int* __restrict__ tcnt, int ng,
            const float* __restrict__ W2, unsigned short* __restrict__ w2t,
            const float* __restrict__ W3, unsigned short* __restrict__ w3t) {
    __shared__ __align__(16) char lds[16384];
    int bid = blockIdx.x, lane = threadIdx.x;

    if (AUX && bid >= ng) {
        int a = bid - ng;
        if (a < 2048) {          // W2: (8,1024,1024) -> (8,1024,1024); 256 tiles/e
            trans64(W2, w2t, H_DIM, H_DIM, H_DIM, a >> 8, (a & 255) >> 4, a & 15,
                    (unsigned short*)lds, lane, 64);
        } else if (a < 2560) {   // W3: (8,1024,257) cols 0..255 -> (8,320,1024)
            int b = a - 2048;
            trans64(W3, w3t, H_DIM, OUT_DIM, W3ROWS, b >> 6, (b & 63) >> 2, b & 3,
                    (unsigned short*)lds, lane, 64);
        } else {                 // W3 reward column -> w3t row 256 (8 blocks)
            int e = a - 2560;
#pragma unroll
            for (int p = 0; p < 16; p++) {
                int k = p * 64 + lane;
                w3t[((size_t)e * W3ROWS + 256) * H_DIM + k] =
                    f2bf(W3[((size_t)e * H_DIM + k) * OUT_DIM + 256]);
            }
        }
        return;
    }

    int t = bid % MAXT, ny = bid / MAXT;
    int cnt = tcnt[t];
    if (cnt == 0) return;
    int e = te[t], p0 = tp0[t];
    int n0 = ny * 64;
    constexpr int NI = K / 32;

    // staging: lane covers LDS slot (row = g*16 + (lane>>2), chunk = lane&3)
    int r  = lane >> 2;
    int cg = (lane & 3) ^ ((r >> 1) & 3);
    const unsigned short* aP[4];
    const unsigned short* bP[4];
#pragma unroll
    for (int g = 0; g < 4; g++) {
        int rm = g * 16 + r;
        int rc = rm < cnt ? rm : cnt - 1;            // clamp; masked in epilogue
        long ar = GATHER ? order[p0 + rc] : (p0 + rc);
        aP[g] = Abase + (size_t)ar * K + cg * 8;
        bP[g] = Wt + ((size_t)e * wtRows + n0 + rm) * K + cg * 8;
    }
    auto stage = [&](int k0, int sb) {
#pragma unroll
        for (int g = 0; g < 4; g++) {
            gload_lds16(aP[g] + k0, lds + sb + g * 1024 + lane * 16);
            gload_lds16(bP[g] + k0, lds + sb + 4096 + g * 1024 + lane * 16);
        }
    };

    f32x4 acc[4][4];
#pragma unroll
    for (int i = 0; i < 4; i++)
#pragma unroll
        for (int j = 0; j < 4; j++) acc[i][j] = (f32x4)0.f;

    const int fm   = lane & 15;
    const int koff = ((lane >> 4) ^ ((fm >> 1) & 3)) * 8;  // swizzled k-chunk

    stage(0, 0);
    for (int it = 0; it < NI; ++it) {
        __syncthreads();                 // drains stage(it); stage(it+1) then flies over compute(it)
        if (it + 1 < NI) stage((it + 1) * 32, ((it + 1) & 1) * 8192);
        const unsigned short* As = (const unsigned short*)(lds + (it & 1) * 8192);
        const unsigned short* Bs = As + 2048;

        bf16x8 af[4], bf[4];
#pragma unroll
        for (int i = 0; i < 4; i++)
            af[i] = *(const bf16x8*)&As[(i * 16 + fm) * 32 + koff];
#pragma unroll
        for (int j = 0; j < 4; j++)
            bf[j] = *(const bf16x8*)&Bs[(j * 16 + fm) * 32 + koff];
#pragma unroll
        for (int i = 0; i < 4; i++)
#pragma unroll
            for (int j = 0; j < 4; j++)
                acc[i][j] = __builtin_amdgcn_mfma_f32_16x16x32_bf16(
                    af[i], bf[j], acc[i][j], 0, 0, 0);
    }

    // epilogue: C/D mapping col = lane&15, row = (lane>>4)*4 + reg
    int col = lane & 15, rq = lane >> 4;
#pragma unroll
    for (int j = 0; j < 4; j++) {
        int n = n0 + j * 16 + col;
        float bv = (MODE == 0) ? bias[e * bstride + n]
                               : ((n <= 256) ? bias[e * bstride + n] : 0.f);
#pragma unroll
        for (int i = 0; i < 4; i++) {
#pragma unroll
            for (int rr = 0; rr < 4; rr++) {
                int m = i * 16 + rq * 4 + rr;
                if (m < cnt) {
                    float v = acc[i][j][rr] + bv;
                    if (MODE == 0) {
                        Hout[(size_t)(p0 + m) * H_DIM + n] = f2bf(fmaxf(v, 0.f));
                    } else {
                        int row = order[p0 + m];
                        if (n < 256) {
                            size_t o = (size_t)row * 256 + n;
                            Out[o] = state[o] + v;
                        } else if (n == 256) {
                            Out[(size_t)B_SZ * 256 + row] = v;   // reward
                        }
                    }
                }
            }
        }
    }
}

// ---------------------------------------------------------------------------
extern "C" void kernel_launch(void* const* d_in, const int* in_sizes, int n_in,
                              void* d_out, int out_size, void* d_ws, size_t ws_size,
                              hipStream_t stream) {
    const float* state  = (const float*)d_in[0];
    const float* action = (const float*)d_in[1];
    const int*   idx    = (const int*)d_in[2];
    const float* W1     = (const float*)d_in[3];
    const float* b1     = (const float*)d_in[4];
    const float* W2     = (const float*)d_in[5];
    const float* b2     = (const float*)d_in[6];
    const float* W3     = (const float*)d_in[7];
    const float* b3     = (const float*)d_in[8];
    float* out = (float*)d_out;

    char* ws = (char*)d_ws;
    size_t off = 0;
    auto alloc = [&](size_t bytes) -> void* {
        void* p = ws + off;
        off = (off + bytes + 255) & ~(size_t)255;
        return p;
    };
    unsigned short* xb  = (unsigned short*)alloc((size_t)B_SZ * IN_DIM * 2);
    unsigned short* w1t = (unsigned short*)alloc((size_t)E_NUM * H_DIM * IN_DIM * 2);
    unsigned short* w2t = (unsigned short*)alloc((size_t)E_NUM * H_DIM * H_DIM * 2);
    unsigned short* w3t = (unsigned short*)alloc((size_t)E_NUM * W3ROWS * H_DIM * 2);
    unsigned short* h1  = (unsigned short*)alloc((size_t)B_SZ * H_DIM * 2);
    unsigned short* h2  = (unsigned short*)alloc((size_t)B_SZ * H_DIM * 2);
    int* order = (int*)alloc(B_SZ * 4);
    int* te    = (int*)alloc(MAXT * 4);
    int* tp0   = (int*)alloc(MAXT * 4);
    int* tcnt  = (int*)alloc(MAXT * 4);

    // prep0: bucket + x-convert + W1 transpose
    k_prep0<<<961, 256, 0, stream>>>(state, action, idx, W1, xb, w1t,
                                     order, te, tp0, tcnt);

    // layer 1 gemm (2176 blocks) + overlapped W2/W3 transposes (2568 blocks)
    k_gemm<IN_DIM, true, 0, true><<<NG12 + NAUX, 64, 0, stream>>>(
        xb, w1t, H_DIM, b1, H_DIM, h1, nullptr, nullptr, order, te, tp0, tcnt,
        NG12, W2, w2t, W3, w3t);
    // layer 2
    k_gemm<H_DIM, false, 0, false><<<NG12, 64, 0, stream>>>(
        h1, w2t, H_DIM, b2, H_DIM, h2, nullptr, nullptr, order, te, tp0, tcnt,
        NG12, nullptr, nullptr, nullptr, nullptr);
    // layer 3 + fused reward: (B,1024) x (1024, 320-padded)
    k_gemm<H_DIM, false, 1, false><<<NG3, 64, 0, stream>>>(
        h2, w3t, W3ROWS, b3, OUT_DIM, nullptr, out, state, order, te, tp0, tcnt,
        NG3, nullptr, nullptr, nullptr, nullptr);
}